// Round 10
// baseline (107.498 us; speedup 1.0000x reference)
//
#include <hip/hip_runtime.h>
#include <hip/hip_bf16.h>

// RetinaNet focal classification loss, MI355X. Output: scalar f32.
//
// Round-10: attack the VGPR occupancy bucket. gfx950 waves/SIMD halve at
// VGPR 64/128/256; r7/r9 sat at 64/68 VGPR -> 4 waves/SIMD (Occ ~21%), and
// real VALU issue occupancy was ~39%. Changes vs r9:
//  - pv[8] prefetch dropped (probs loaded in epilogue)  -> -8 live VGPRs
//  - gt table + fast-flag built in prep kernel; main stages it with one
//    float4 load per thread (t<64) + 1 barrier (no wave0 build/ballot)
//  - __launch_bounds__(256,8) pins VGPR <= 64 (live set ~56 now; no outer
//    loop so no r4-style LICM spill; slow path may spill but never runs)
//  - full j-unroll kept (r7 beat unroll-4)
//
// Fast path (all labels zero): division-free predicates
//   iou>=0.5 <=> fma(inter,3,-ga) >= area_a+eps
//   iou<0.4  <=> fma(inter,3.5,-ga) < area_a+eps
// -> 13 VALU ops/pair, independent fmax chains. Slow path: exact argmax.
//
// ws floats: [0..15] loss sums, [16..31] pos counts,
//   [32..] packed gt: (b,j) -> 2 float4s {x1,y1,x2,y2} {-ga,ga,lab,flag(j==0)}

#define A_N 200000
#define B_N 16
#define G_N 32
#define APT 8
#define BLK 256
#define TILE (BLK * APT)                 // 2048
#define NBX ((A_N + TILE - 1) / TILE)    // 98

#define C_POS (0.25f * 0.69314718f)      // alpha * ln2   (log2 -> ln fold)
#define C_NEG (0.75f * 0.69314718f)      // (1-alpha) * ln2

// ---------------- prep: zero accumulators + packed gt table + flags ----------------
__global__ void rnl_prep(const float* __restrict__ y_true, float* __restrict__ ws) {
    const int t = threadIdx.x;            // 512 threads == B_N*G_N
    if (t < 2 * B_N) ws[t] = 0.0f;
    {
        float cx = y_true[t * 5 + 0];
        float cy = y_true[t * 5 + 1];
        float w  = y_true[t * 5 + 2];
        float h  = y_true[t * 5 + 3];
        float lb = y_true[t * 5 + 4];
        float x1 = cx - 0.5f * w, y1 = cy - 0.5f * h;
        float x2 = cx + 0.5f * w, y2 = cy + 0.5f * h;
        float ga = (x2 - x1) * (y2 - y1);
        float4* g = reinterpret_cast<float4*>(ws + 2 * B_N);
        g[t * 2 + 0] = make_float4(x1, y1, x2, y2);
        g[t * 2 + 1] = make_float4(-ga, ga, lb, 0.0f);
    }
    __syncthreads();
    if (t < B_N) {                        // per-image fast flag -> entry0 meta.w
        bool allz = true;
        for (int j = 0; j < G_N; ++j)
            allz = allz && (y_true[(t * G_N + j) * 5 + 4] == 0.0f);
        ws[2 * B_N + (t * G_N) * 8 + 7] = allz ? 1.0f : 0.0f;
    }
}

// ---------------- main ----------------
__launch_bounds__(BLK, 8)
__global__ void rnl_main(const float4* __restrict__ anchors,
                         const float* __restrict__ probs,
                         const float4* __restrict__ gtab,   // (ws+32) as float4
                         float* __restrict__ ws) {
    __shared__ float4 sgt[G_N * 2];       // interleaved {box, meta} per entry

    const int b = blockIdx.y;
    const int t = threadIdx.x;

    if (t < 2 * G_N) sgt[t] = gtab[b * (2 * G_N) + t];
    __syncthreads();

    const bool fast = (sgt[1].w != 0.0f); // entry0 meta.w = per-image flag
    const int base = blockIdx.x * TILE + t;

    float loss = 0.0f, cnt = 0.0f;

    // anchors resident in regs for the whole j-loop (32 VGPR)
    float ax[APT], ay[APT], az[APT], aw[APT];
    #pragma unroll
    for (int k = 0; k < APT; ++k) {
        int idx  = base + k * BLK;
        int idxc = idx < A_N ? idx : A_N - 1;
        float4 an = anchors[idxc];
        ax[k] = an.x; ay[k] = an.y; az[k] = an.z; aw[k] = an.w;
    }

    if (fast) {
        // ---- fast path: all labels zero -> 13 ops/pair, fmax-chain trackers
        float m1[APT], m2[APT];
        #pragma unroll
        for (int k = 0; k < APT; ++k) { m1[k] = -1e30f; m2[k] = -1e30f; }

        #pragma unroll
        for (int j = 0; j < G_N; ++j) {
            float4 gb  = sgt[2 * j];
            float  nga = sgt[2 * j + 1].x;
            #pragma unroll
            for (int k = 0; k < APT; ++k) {
                float ltx = fmaxf(ax[k], gb.x);
                float lty = fmaxf(ay[k], gb.y);
                float rbx = fminf(az[k], gb.z);
                float rby = fminf(aw[k], gb.w);
                float iw  = fmaxf(rbx - ltx, 0.0f);
                float ih  = fmaxf(rby - lty, 0.0f);
                float inter = iw * ih;
                m1[k] = fmaxf(m1[k], fmaf(inter, 3.0f, nga));
                m2[k] = fmaxf(m2[k], fmaf(inter, 3.5f, nga));
            }
        }
        #pragma unroll
        for (int k = 0; k < APT; ++k) {
            int idx  = base + k * BLK;
            bool valid = idx < A_N;
            int idxc = valid ? idx : A_N - 1;
            float sa = (az[k] - ax[k]) * (aw[k] - ay[k]) + 1e-8f;
            bool pos = m1[k] >= sa;             // max iou >= 0.5
            bool neg = m2[k] <  sa;             // max iou <  0.4
            float p = __builtin_amdgcn_fmed3f(probs[b * A_N + idxc], 1e-7f, 1.0f - 1e-7f);
            float q = 1.0f - p;
            float x = pos ? p : q;              // label==0 -> pos implies target hit
            float w = pos ? C_POS * q * q : C_NEG * p * p;
            float l = w * (-__log2f(x));
            l = ((pos | neg) && valid) ? l : 0.0f;
            loss += l;
            cnt  += (pos && valid) ? 1.0f : 0.0f;
        }
    } else {
        // ---- slow path: exact argmax + label (general correctness)
        const float lab0 = sgt[1].z;
        float bi[APT], bS[APT], bl[APT];
        #pragma unroll
        for (int k = 0; k < APT; ++k) { bi[k] = 0.0f; bS[k] = 1.0f; bl[k] = lab0; }

        #pragma unroll
        for (int j = 0; j < G_N; ++j) {
            float4 gb = sgt[2 * j];
            float4 gm = sgt[2 * j + 1];         // {-ga, ga, lab, .}
            #pragma unroll
            for (int k = 0; k < APT; ++k) {
                float ltx = fmaxf(ax[k], gb.x);
                float lty = fmaxf(ay[k], gb.y);
                float rbx = fminf(az[k], gb.z);
                float rby = fminf(aw[k], gb.w);
                float iw  = fmaxf(rbx - ltx, 0.0f);
                float ih  = fmaxf(rby - lty, 0.0f);
                float inter = iw * ih;
                float sa = (az[k] - ax[k]) * (aw[k] - ay[k]) + 1e-8f;
                float S  = sa + gm.y;
                // iou_j > iou_best <=> inter_j*S_best > inter_best*S_j
                bool better = inter * bS[k] > bi[k] * S;
                bi[k] = better ? inter : bi[k];
                bS[k] = better ? S     : bS[k];
                bl[k] = better ? gm.z  : bl[k];
            }
        }
        #pragma unroll
        for (int k = 0; k < APT; ++k) {
            int idx  = base + k * BLK;
            bool valid = idx < A_N;
            int idxc = valid ? idx : A_N - 1;
            bool pos = 3.0f * bi[k] >= bS[k];   // max iou >= 0.5
            bool neg = 3.5f * bi[k] <  bS[k];   // max iou <  0.4
            bool tp  = pos && (bl[k] == 0.0f);  // one_hot(assigned, C=1) hit
            float p = __builtin_amdgcn_fmed3f(probs[b * A_N + idxc], 1e-7f, 1.0f - 1e-7f);
            float q = 1.0f - p;
            float x = tp ? p : q;
            float w = tp ? C_POS * q * q : C_NEG * p * p;
            float l = w * (-__log2f(x));
            l = ((pos | neg) && valid) ? l : 0.0f;
            loss += l;
            cnt  += (pos && valid) ? 1.0f : 0.0f;
        }
    }

    // block reduction: wave shuffle, then cross-wave via LDS, 2 atomics/block
    #pragma unroll
    for (int off = 32; off > 0; off >>= 1) {
        loss += __shfl_down(loss, off);
        cnt  += __shfl_down(cnt, off);
    }
    __shared__ float s_l[4], s_c[4];
    int wid  = t >> 6;
    int lane = t & 63;
    if (lane == 0) { s_l[wid] = loss; s_c[wid] = cnt; }
    __syncthreads();
    if (t == 0) {
        atomicAdd(&ws[b],       s_l[0] + s_l[1] + s_l[2] + s_l[3]);
        atomicAdd(&ws[B_N + b], s_c[0] + s_c[1] + s_c[2] + s_c[3]);
    }
}

__global__ void rnl_final(const float* __restrict__ ws, float* __restrict__ out) {
    if (threadIdx.x == 0) {
        float s = 0.0f;
        #pragma unroll
        for (int b = 0; b < B_N; ++b) {
            s += ws[b] / fmaxf(ws[B_N + b], 1.0f);
        }
        out[0] = s * (1.0f / (float)B_N);
    }
}

extern "C" void kernel_launch(void* const* d_in, const int* in_sizes, int n_in,
                              void* d_out, int out_size, void* d_ws, size_t ws_size,
                              hipStream_t stream) {
    const float* y_true     = (const float*)d_in[0];
    const float* y_classifs = (const float*)d_in[1];
    // d_in[2] = y_regressions: unused by the loss
    const float* anchors    = (const float*)d_in[3];
    float* ws = (float*)d_ws;

    rnl_prep<<<1, B_N * G_N, 0, stream>>>(y_true, ws);

    dim3 grid(NBX, B_N);
    rnl_main<<<grid, BLK, 0, stream>>>((const float4*)anchors, y_classifs,
                                       (const float4*)(ws + 2 * B_N), ws);

    rnl_final<<<1, 64, 0, stream>>>(ws, (float*)d_out);
}

// Round 11
// 67.470 us; speedup vs baseline: 1.5933x; 1.5933x over previous
//
#include <hip/hip_runtime.h>
#include <hip/hip_bf16.h>

// RetinaNet focal classification loss, MI355X. Output: scalar f32.
//
// Round-11 = round-7 (best, 40us main) with the reduction tail rebuilt:
//  - NO global atomics: each block writes one float2 partial {loss,cnt} to ws
//    (1568 coalesced stores). All 1568 equal-work blocks finish simultaneously;
//    r7 queued 98-deep same-address atomic chains + retire-waits at that moment.
//  - reduce kernel (1 block) does per-image sums + mean; merges old rnl_final.
//  - memset node dropped (nothing needs zeroing; partials are pure writes).
//  => 2 graph nodes instead of 4. Main kernel body is r7-identical (clean A/B
//     on the reduction-tail theory).
//
// Fast path (all labels zero, __ballot-detected): division-free predicates
//   iou>=0.5 <=> fma(inter,3,-ga) >= area_a+eps
//   iou<0.4  <=> fma(inter,3.5,-ga) < area_a+eps
// -> 13 VALU ops/pair, independent fmax chains. Slow path: exact argmax.
//
// ws layout: float2 partials[16][98]  (b-major), nothing else.

#define A_N 200000
#define B_N 16
#define G_N 32
#define APT 8
#define BLK 256
#define TILE (BLK * APT)                 // 2048
#define NBX ((A_N + TILE - 1) / TILE)    // 98

#define C_POS (0.25f * 0.69314718f)      // alpha * ln2   (log2 -> ln fold)
#define C_NEG (0.75f * 0.69314718f)      // (1-alpha) * ln2

__launch_bounds__(BLK)
__global__ void rnl_main(const float4* __restrict__ anchors,
                         const float* __restrict__ probs,
                         const float* __restrict__ y_true,
                         float2* __restrict__ partials) {
    __shared__ float4 sbox[G_N];        // gt corners {x1,y1,x2,y2}
    __shared__ float  snga[G_N];        // -ga
    __shared__ float  sga[G_N];         // ga   (slow path)
    __shared__ float  slab[G_N];        // label (slow path)
    __shared__ float  sraw[G_N * 5];
    __shared__ int    sflag;

    const int b = blockIdx.y;
    const int t = threadIdx.x;

    if (t < G_N * 5) sraw[t] = y_true[b * (G_N * 5) + t];
    __syncthreads();
    if (t < 64) {                          // wave 0 builds gt table + flag
        float lb = 0.0f;
        if (t < G_N) {
            float cx = sraw[t * 5 + 0], cy = sraw[t * 5 + 1];
            float w  = sraw[t * 5 + 2], h  = sraw[t * 5 + 3];
            lb = sraw[t * 5 + 4];
            float x1 = cx - 0.5f * w, y1 = cy - 0.5f * h;
            float x2 = cx + 0.5f * w, y2 = cy + 0.5f * h;
            float ga = (x2 - x1) * (y2 - y1);
            sbox[t] = make_float4(x1, y1, x2, y2);
            snga[t] = -ga; sga[t] = ga; slab[t] = lb;
        }
        unsigned long long bal = __ballot(lb != 0.0f);
        if (t == 0) sflag = (bal == 0ULL) ? 1 : 0;
    }
    __syncthreads();

    const int base = blockIdx.x * TILE + t;
    const float lab0 = slab[0];

    float loss = 0.0f, cnt = 0.0f;

    // anchors + probs resident in regs for the whole j-loop
    float ax[APT], ay[APT], az[APT], aw[APT], pv[APT];
    #pragma unroll
    for (int k = 0; k < APT; ++k) {
        int idx  = base + k * BLK;
        int idxc = idx < A_N ? idx : A_N - 1;
        float4 an = anchors[idxc];
        ax[k] = an.x; ay[k] = an.y; az[k] = an.z; aw[k] = an.w;
        pv[k] = probs[b * A_N + idxc];
    }

    if (sflag) {
        // ---- fast path: all labels zero -> 13 ops/pair, fmax-chain trackers
        float m1[APT], m2[APT];
        #pragma unroll
        for (int k = 0; k < APT; ++k) { m1[k] = -1e30f; m2[k] = -1e30f; }

        #pragma unroll
        for (int j = 0; j < G_N; ++j) {
            float4 gb  = sbox[j];
            float  nga = snga[j];
            #pragma unroll
            for (int k = 0; k < APT; ++k) {
                float ltx = fmaxf(ax[k], gb.x);
                float lty = fmaxf(ay[k], gb.y);
                float rbx = fminf(az[k], gb.z);
                float rby = fminf(aw[k], gb.w);
                float iw  = fmaxf(rbx - ltx, 0.0f);
                float ih  = fmaxf(rby - lty, 0.0f);
                float inter = iw * ih;
                m1[k] = fmaxf(m1[k], fmaf(inter, 3.0f, nga));
                m2[k] = fmaxf(m2[k], fmaf(inter, 3.5f, nga));
            }
        }
        #pragma unroll
        for (int k = 0; k < APT; ++k) {
            bool valid = (base + k * BLK) < A_N;
            float sa = (az[k] - ax[k]) * (aw[k] - ay[k]) + 1e-8f;
            bool pos = m1[k] >= sa;             // max iou >= 0.5
            bool neg = m2[k] <  sa;             // max iou <  0.4
            float p = __builtin_amdgcn_fmed3f(pv[k], 1e-7f, 1.0f - 1e-7f);
            float q = 1.0f - p;
            float x = pos ? p : q;              // label==0 -> pos implies target hit
            float w = pos ? C_POS * q * q : C_NEG * p * p;
            float l = w * (-__log2f(x));
            l = ((pos | neg) && valid) ? l : 0.0f;
            loss += l;
            cnt  += (pos && valid) ? 1.0f : 0.0f;
        }
    } else {
        // ---- slow path: exact argmax + label (general correctness)
        float bi[APT], bS[APT], bl[APT];
        #pragma unroll
        for (int k = 0; k < APT; ++k) { bi[k] = 0.0f; bS[k] = 1.0f; bl[k] = lab0; }

        #pragma unroll
        for (int j = 0; j < G_N; ++j) {
            float4 gb = sbox[j];
            float  ga = sga[j];
            float  lb = slab[j];
            #pragma unroll
            for (int k = 0; k < APT; ++k) {
                float ltx = fmaxf(ax[k], gb.x);
                float lty = fmaxf(ay[k], gb.y);
                float rbx = fminf(az[k], gb.z);
                float rby = fminf(aw[k], gb.w);
                float iw  = fmaxf(rbx - ltx, 0.0f);
                float ih  = fmaxf(rby - lty, 0.0f);
                float inter = iw * ih;
                float sa = (az[k] - ax[k]) * (aw[k] - ay[k]) + 1e-8f;
                float S  = sa + ga;
                // iou_j > iou_best <=> inter_j*S_best > inter_best*S_j
                bool better = inter * bS[k] > bi[k] * S;
                bi[k] = better ? inter : bi[k];
                bS[k] = better ? S     : bS[k];
                bl[k] = better ? lb    : bl[k];
            }
        }
        #pragma unroll
        for (int k = 0; k < APT; ++k) {
            bool valid = (base + k * BLK) < A_N;
            bool pos = 3.0f * bi[k] >= bS[k];   // max iou >= 0.5
            bool neg = 3.5f * bi[k] <  bS[k];   // max iou <  0.4
            bool tp  = pos && (bl[k] == 0.0f);  // one_hot(assigned, C=1) hit
            float p = __builtin_amdgcn_fmed3f(pv[k], 1e-7f, 1.0f - 1e-7f);
            float q = 1.0f - p;
            float x = tp ? p : q;
            float w = tp ? C_POS * q * q : C_NEG * p * p;
            float l = w * (-__log2f(x));
            l = ((pos | neg) && valid) ? l : 0.0f;
            loss += l;
            cnt  += (pos && valid) ? 1.0f : 0.0f;
        }
    }

    // block reduction: wave shuffle, then cross-wave via LDS, ONE float2 store
    #pragma unroll
    for (int off = 32; off > 0; off >>= 1) {
        loss += __shfl_down(loss, off);
        cnt  += __shfl_down(cnt, off);
    }
    __shared__ float s_l[4], s_c[4];
    int wid  = t >> 6;
    int lane = t & 63;
    if (lane == 0) { s_l[wid] = loss; s_c[wid] = cnt; }
    __syncthreads();
    if (t == 0) {
        float L = s_l[0] + s_l[1] + s_l[2] + s_l[3];
        float C = s_c[0] + s_c[1] + s_c[2] + s_c[3];
        partials[b * NBX + blockIdx.x] = make_float2(L, C);   // no atomics
    }
}

// ---------------- reduce: per-image sums + mean (merges old final) ----------------
__global__ void rnl_reduce(const float2* __restrict__ partials,
                           float* __restrict__ out) {
    const int t = threadIdx.x;          // 256 = 16 images x 16 lanes
    const int img = t >> 4, lane16 = t & 15;
    float L = 0.0f, C = 0.0f;
    for (int i = lane16; i < NBX; i += 16) {
        float2 p = partials[img * NBX + i];
        L += p.x; C += p.y;
    }
    #pragma unroll
    for (int m = 8; m > 0; m >>= 1) {
        L += __shfl_xor(L, m, 16);
        C += __shfl_xor(C, m, 16);
    }
    __shared__ float sl[B_N], sc[B_N];
    if (lane16 == 0) { sl[img] = L; sc[img] = C; }
    __syncthreads();
    if (t == 0) {
        float s = 0.0f;
        #pragma unroll
        for (int b = 0; b < B_N; ++b) s += sl[b] / fmaxf(sc[b], 1.0f);
        out[0] = s * (1.0f / (float)B_N);
    }
}

extern "C" void kernel_launch(void* const* d_in, const int* in_sizes, int n_in,
                              void* d_out, int out_size, void* d_ws, size_t ws_size,
                              hipStream_t stream) {
    const float* y_true     = (const float*)d_in[0];
    const float* y_classifs = (const float*)d_in[1];
    // d_in[2] = y_regressions: unused by the loss
    const float* anchors    = (const float*)d_in[3];
    float2* partials = (float2*)d_ws;

    dim3 grid(NBX, B_N);
    rnl_main<<<grid, BLK, 0, stream>>>((const float4*)anchors, y_classifs,
                                       y_true, partials);

    rnl_reduce<<<1, 256, 0, stream>>>(partials, (float*)d_out);
}